// Round 5
// baseline (52.626 us; speedup 1.0000x reference)
//
#include <hip/hip_runtime.h>
#include <hip/hip_bf16.h>

#define B_SZ   256
#define N_IN   128
#define F_IN   64
#define G_SZ   128
#define F_OUT  64
#define S_SZ   16
#define K_TOT  1024   // S_SZ * F_IN
#define NSTEP  16     // K-steps of 64

#define THREADS 256   // 4 waves; each wave owns 16 m-rows x 64 n-cols
#define M_TILE  64    // per block
// grid = 128 g * 4 m-tiles = 512 blocks = 2 blocks/CU

typedef __attribute__((ext_vector_type(8))) short short8;  // 8 bf16
typedef __attribute__((ext_vector_type(4))) float f32x4;
typedef unsigned short u16;
typedef unsigned int   u32;

#define XN   (B_SZ * N_IN * F_IN)          // 2,097,152 x elements
#define WN   (G_SZ * F_OUT * K_TOT)        // 8,388,608 W elements
#define XN8  (XN / 8)                      // 262,144
#define TOT8 ((XN + WN) / 8)               // 1,310,720

static __device__ __forceinline__ u32 packbf2(float a, float b) {
    __hip_bfloat162 h = __float22bfloat162_rn(make_float2(a, b));
    union { __hip_bfloat162 h; u32 u; } c; c.h = h;
    return c.u;
}

// ---- pass 1: convert x and W (fp32 -> bf16), same layouts ----
__global__ __launch_bounds__(256)
void convert_kernel(const float* __restrict__ x, const float* __restrict__ W,
                    u16* __restrict__ xbf, u16* __restrict__ wbf) {
    const int i = blockIdx.x * 256 + threadIdx.x;   // 8-element chunk id
    const float* src;
    u16* dst;
    int off;
    if (i < XN8) { src = x; dst = xbf; off = i * 8; }
    else         { src = W; dst = wbf; off = (i - XN8) * 8; }
    const float4 v0 = *reinterpret_cast<const float4*>(src + off);
    const float4 v1 = *reinterpret_cast<const float4*>(src + off + 4);
    uint4 p;
    p.x = packbf2(v0.x, v0.y); p.y = packbf2(v0.z, v0.w);
    p.z = packbf2(v1.x, v1.y); p.w = packbf2(v1.z, v1.w);
    *reinterpret_cast<uint4*>(dst + off) = p;
}

// ---- pass 2: barrier-free, LDS-free grouped GEMM ----
// Every A/B MFMA fragment is one contiguous 16B global load in frag layout.
__global__ __launch_bounds__(THREADS)
void sparse_linear_kernel(const u16*  __restrict__ xbf,
                          const u16*  __restrict__ wbf,
                          const int*  __restrict__ idx,
                          const float* __restrict__ bias,
                          float*       __restrict__ out)
{
    const int blk   = blockIdx.x;
    const int g     = blk & 127;      // blocks sharing g are 128 apart -> same XCD
    const int mt    = blk >> 7;       // 0..3
    const int bbase = mt * M_TILE;

    const int tid  = threadIdx.x;
    const int wave = tid >> 6;        // 0..3 -> m rows [wave*16, wave*16+16)
    const int lane = tid & 63;
    const int lmod = lane & 15;
    const int ldiv = lane >> 4;

    int rows[NSTEP];
    #pragma unroll
    for (int s = 0; s < NSTEP; ++s) rows[s] = idx[g * S_SZ + s];

    // A: xbf[b][n][f], b-stride 8192, n-stride 64.  frag(m16, k32=ks):
    //   lane reads f = ks*32 + ldiv*8 .. +8 of row (bbase+wave*16+lmod, rows[t])
    const u16* aBase = xbf + (size_t)(bbase + wave * 16 + lmod) * (N_IN * F_IN)
                           + ldiv * 8;
    // B: wbf[g][o][k], o-stride 1024.  frag(n16=ni, k32=ks):
    //   lane reads k = t*64 + ks*32 + ldiv*8 .. +8 of row o = ni*16+lmod
    const u16* wBase = wbf + (size_t)g * (F_OUT * K_TOT)
                           + (size_t)lmod * K_TOT + ldiv * 8;

    f32x4 acc[4] = {};                 // 4 n-frags (16x16 each), 16 m rows

    short8 Af[3][2];                   // [set][ks]
    short8 Bf[3][4][2];                // [set][ni][ks]

    #define LOADT(t, s)                                                        \
        {                                                                      \
            const u16* ap = aBase + rows[t] * F_IN;                            \
            Af[s][0] = *reinterpret_cast<const short8*>(ap);                   \
            Af[s][1] = *reinterpret_cast<const short8*>(ap + 32);              \
            _Pragma("unroll")                                                  \
            for (int ni = 0; ni < 4; ++ni) {                                   \
                const u16* wp = wBase + ni * (16 * K_TOT) + (t) * 64;          \
                Bf[s][ni][0] = *reinterpret_cast<const short8*>(wp);           \
                Bf[s][ni][1] = *reinterpret_cast<const short8*>(wp + 32);      \
            }                                                                  \
        }

    #define COMP(s)                                                            \
        {                                                                      \
            _Pragma("unroll")                                                  \
            for (int ks = 0; ks < 2; ++ks)                                     \
                _Pragma("unroll")                                              \
                for (int ni = 0; ni < 4; ++ni)                                 \
                    acc[ni] = __builtin_amdgcn_mfma_f32_16x16x32_bf16(         \
                        Af[s][ks], Bf[s][ni][ks], acc[ni], 0, 0, 0);           \
        }

    // depth-3 rotation: step t lives in set t%3; no barriers anywhere.
    LOADT(0, 0);
    LOADT(1, 1);
    LOADT(2, 2);
    #pragma unroll
    for (int t = 0; t < NSTEP; ++t) {
        COMP(t % 3);
        if (t + 3 < NSTEP) LOADT(t + 3, t % 3);
    }

    // epilogue: C frag col = lane&15 (o), row = ldiv*4 + r (m)
    const int rowbase = bbase + wave * 16 + ldiv * 4;
    #pragma unroll
    for (int ni = 0; ni < 4; ++ni) {
        const int o  = ni * 16 + lmod;
        const float bv = bias[g * F_OUT + o];
        #pragma unroll
        for (int r = 0; r < 4; ++r) {
            const int brow = rowbase + r;
            out[(size_t)brow * (G_SZ * F_OUT) + g * F_OUT + o] = acc[ni][r] + bv;
        }
    }
}

// ---- fallback (ws too small; never expected to run): naive fp32 ----
__global__ __launch_bounds__(256)
void naive_kernel(const float* __restrict__ x, const int* __restrict__ idx,
                  const float* __restrict__ W, const float* __restrict__ bias,
                  float* __restrict__ out) {
    const int i = blockIdx.x * 256 + threadIdx.x;   // (b, g, o)
    const int o = i & 63, gg = (i >> 6) & 127, b = i >> 13;
    float s = bias[gg * F_OUT + o];
    for (int t = 0; t < S_SZ; ++t) {
        const int r = idx[gg * S_SZ + t];
        #pragma unroll 8
        for (int f = 0; f < F_IN; ++f)
            s += x[(size_t)b * (N_IN * F_IN) + r * F_IN + f]
               * W[(size_t)gg * (F_OUT * K_TOT) + (size_t)o * K_TOT + t * F_IN + f];
    }
    out[i] = s;
}

extern "C" void kernel_launch(void* const* d_in, const int* in_sizes, int n_in,
                              void* d_out, int out_size, void* d_ws, size_t ws_size,
                              hipStream_t stream) {
    const float* x    = (const float*)d_in[0];
    const int*   idx  = (const int*)d_in[1];
    const float* W    = (const float*)d_in[2];
    const float* bias = (const float*)d_in[3];
    float*       out  = (float*)d_out;

    const size_t need = (size_t)(XN + WN) * sizeof(u16);   // 21 MB
    if (ws_size >= need) {
        u16* xbf = (u16*)d_ws;
        u16* wbf = xbf + XN;
        convert_kernel<<<dim3(TOT8 / 256), dim3(256), 0, stream>>>(x, W, xbf, wbf);
        sparse_linear_kernel<<<dim3(G_SZ * (B_SZ / M_TILE)), dim3(THREADS), 0, stream>>>(
            xbf, wbf, idx, bias, out);
    } else {
        naive_kernel<<<dim3((B_SZ * G_SZ * F_OUT) / 256), dim3(256), 0, stream>>>(
            x, idx, W, bias, out);
    }
}

// Round 6
// 23.656 us; speedup vs baseline: 2.2247x; 2.2247x over previous
//
#include <hip/hip_runtime.h>
#include <hip/hip_bf16.h>

#define B_SZ   256
#define N_IN   128
#define F_IN   64
#define G_SZ   128
#define F_OUT  64
#define S_SZ   16
#define K_TOT  1024   // S_SZ * F_IN

#define M_TILE 128
#define BK     64
#define NSTEP  16     // K_TOT / BK
#define THREADS 512   // 8 waves: wave grid 4 (M) x 2 (N)

// LDS row stride in bf16 elements: 64 + 8 pad = 72 (144 B rows): <=2-way
// bank aliasing on ds_read_b128 (free per m136)
#define LDSTRIDE 72

typedef __attribute__((ext_vector_type(8))) short short8;  // 8 bf16
typedef __attribute__((ext_vector_type(4))) float f32x4;
typedef unsigned short u16;
typedef unsigned int   u32;

static __device__ __forceinline__ u32 packbf2(float a, float b) {
    // low 16 = a, high 16 = b (RNE); compiler emits v_cvt_pk_bf16_f32
    __hip_bfloat162 h = __float22bfloat162_rn(make_float2(a, b));
    union { __hip_bfloat162 h; u32 u; } c; c.h = h;
    return c.u;
}

__global__ __launch_bounds__(THREADS)
void sparse_linear_kernel(const float* __restrict__ x,
                          const int*   __restrict__ idx,
                          const float* __restrict__ W,
                          const float* __restrict__ bias,
                          float*       __restrict__ out)
{
    __shared__ u16 Alds[2][M_TILE * LDSTRIDE];
    __shared__ u16 Wlds[2][F_OUT * LDSTRIDE];

    const int blk   = blockIdx.x;
    const int g     = blk & 127;   // blk, blk+128 share W[g]; 128%8==0 -> same XCD
    const int mt    = blk >> 7;
    const int bbase = mt * M_TILE;

    const int tid  = threadIdx.x;
    const int wave = tid >> 6;
    const int lane = tid & 63;
    const int wr   = wave >> 1;    // 0..3 (M, 32 rows)
    const int wc   = wave & 1;     // 0..1 (N, 32 cols)
    const int lmod = lane & 15;
    const int ldiv = lane >> 4;

    // ---- A staging: 4 chunks, id = tid + i*512 in 0..2047 ----
    const float* aptr[4]; int lofsA[4];
    #pragma unroll
    for (int i = 0; i < 4; ++i) {
        int id = tid + i * THREADS;
        int m  = id >> 4;                  // 0..127
        int f  = (id & 15) << 2;           // float col
        aptr[i]  = x + (size_t)(bbase + m) * (N_IN * F_IN) + f;
        lofsA[i] = m * (LDSTRIDE * 2) + f * 2;
    }
    // ---- W staging: 2 chunks ----
    const float* wptr[2]; int lofsW[2];
    #pragma unroll
    for (int i = 0; i < 2; ++i) {
        int id = tid + i * THREADS;
        int o  = id >> 4;                  // 0..63
        int f  = (id & 15) << 2;
        wptr[i]  = W + (size_t)g * (F_OUT * K_TOT) + (size_t)o * K_TOT + f;
        lofsW[i] = o * (LDSTRIDE * 2) + f * 2;
    }

    int rows[NSTEP];
    #pragma unroll
    for (int s = 0; s < NSTEP; ++s) rows[s] = idx[g * S_SZ + s];  // uniform -> SGPR

    f32x4  acc[2][2] = {};
    float4 ra[3][4], rw[3][2];             // depth-3 register sets

    #define LOADT(t, s)                                                        \
        {                                                                      \
            const int row = rows[t];                                           \
            _Pragma("unroll")                                                  \
            for (int i = 0; i < 4; ++i)                                        \
                ra[s][i] = *reinterpret_cast<const float4*>(aptr[i] + row * F_IN); \
            _Pragma("unroll")                                                  \
            for (int i = 0; i < 2; ++i)                                        \
                rw[s][i] = *reinterpret_cast<const float4*>(wptr[i] + (t) * BK);   \
        }

    #define STORET(s, buf)                                                     \
        {                                                                      \
            _Pragma("unroll")                                                  \
            for (int i = 0; i < 4; ++i) {                                      \
                uint2 p;                                                       \
                p.x = packbf2(ra[s][i].x, ra[s][i].y);                         \
                p.y = packbf2(ra[s][i].z, ra[s][i].w);                         \
                *reinterpret_cast<uint2*>(                                     \
                    reinterpret_cast<char*>(Alds[buf]) + lofsA[i]) = p;        \
            }                                                                  \
            _Pragma("unroll")                                                  \
            for (int i = 0; i < 2; ++i) {                                      \
                uint2 p;                                                       \
                p.x = packbf2(rw[s][i].x, rw[s][i].y);                         \
                p.y = packbf2(rw[s][i].z, rw[s][i].w);                         \
                *reinterpret_cast<uint2*>(                                     \
                    reinterpret_cast<char*>(Wlds[buf]) + lofsW[i]) = p;        \
            }                                                                  \
        }

    #define COMPUTE(buf)                                                       \
        {                                                                      \
            _Pragma("unroll")                                                  \
            for (int ks = 0; ks < 2; ++ks) {                                   \
                const int kb = ks * 32 + (ldiv << 3);                          \
                short8 a[2], bfr[2];                                           \
                _Pragma("unroll")                                              \
                for (int mi = 0; mi < 2; ++mi)                                 \
                    a[mi] = *reinterpret_cast<const short8*>(                  \
                        reinterpret_cast<const char*>(Alds[buf]) +             \
                        (wr * 32 + mi * 16 + lmod) * (LDSTRIDE * 2) + kb * 2); \
                _Pragma("unroll")                                              \
                for (int ni = 0; ni < 2; ++ni)                                 \
                    bfr[ni] = *reinterpret_cast<const short8*>(                \
                        reinterpret_cast<const char*>(Wlds[buf]) +             \
                        (wc * 32 + ni * 16 + lmod) * (LDSTRIDE * 2) + kb * 2); \
                _Pragma("unroll")                                              \
                for (int mi = 0; mi < 2; ++mi)                                 \
                    _Pragma("unroll")                                          \
                    for (int ni = 0; ni < 2; ++ni)                             \
                        acc[mi][ni] = __builtin_amdgcn_mfma_f32_16x16x32_bf16( \
                            a[mi], bfr[ni], acc[mi][ni], 0, 0, 0);             \
            }                                                                  \
        }

    // Barrier WITHOUT the compiler's vmcnt(0) drain: drain only LDS ops
    // (own ds_writes must be visible; own ds_reads of the buffer about to be
    // overwritten must have completed). Global loads stay in flight.
    #define ROLL_BARRIER()                                                     \
        {                                                                      \
            asm volatile("s_waitcnt lgkmcnt(0)" ::: "memory");                 \
            __builtin_amdgcn_s_barrier();                                      \
            asm volatile("" ::: "memory");                                     \
        }

    // ---- prologue: 3 load sets in flight, buffer 0 staged ----
    LOADT(0, 0);
    LOADT(1, 1);
    LOADT(2, 2);
    STORET(0, 0);            // counted wait: only set-0's 6 loads (12 stay in flight)
    ROLL_BARRIER();

    // ---- main loop: rolling depth-3 pipeline, vmcnt never drained to 0 ----
    // step t: regs set t%3, LDS buf t&1
    #pragma unroll
    for (int t = 0; t < NSTEP; ++t) {
        if (t + 3 < NSTEP) LOADT(t + 3, t % 3);          // issue early
        COMPUTE(t & 1);
        if (t + 1 < NSTEP) {
            STORET((t + 1) % 3, (t + 1) & 1);            // waits set t+1 only
            ROLL_BARRIER();
        }
    }

    // ---- epilogue: C frag col = lane&15, row = (lane>>4)*4 + r ----
    const int rowbase = bbase + wr * 32 + (ldiv << 2);
    #pragma unroll
    for (int ni = 0; ni < 2; ++ni) {
        const int o  = wc * 32 + ni * 16 + lmod;
        const float bv = bias[g * F_OUT + o];
        #pragma unroll
        for (int mi = 0; mi < 2; ++mi) {
            #pragma unroll
            for (int r = 0; r < 4; ++r) {
                const int brow = rowbase + mi * 16 + r;
                out[(size_t)brow * (G_SZ * F_OUT) + g * F_OUT + o] = acc[mi][ni][r] + bv;
            }
        }
    }
}

extern "C" void kernel_launch(void* const* d_in, const int* in_sizes, int n_in,
                              void* d_out, int out_size, void* d_ws, size_t ws_size,
                              hipStream_t stream) {
    const float* x    = (const float*)d_in[0];
    const int*   idx  = (const int*)d_in[1];
    const float* W    = (const float*)d_in[2];
    const float* bias = (const float*)d_in[3];
    float*       out  = (float*)d_out;

    sparse_linear_kernel<<<dim3(G_SZ * (B_SZ / M_TILE)), dim3(THREADS), 0, stream>>>(
        x, idx, W, bias, out);
}